// Round 1
// 677.391 us; speedup vs baseline: 1.4117x; 1.4117x over previous
//
#include <hip/hip_runtime.h>

// Problem constants (fixed by setup_inputs)
constexpr int B = 4, C = 3, H = 1080, W = 1920;
constexpr int HW = H * W;
constexpr int N = B * HW;                 // 8,294,400 source pixels
constexpr float MOTION_TH = 25.0f;        // 0.25 * 100
constexpr float EPS = 1e-5f;

// Packed fixed-point accumulator (unchanged, verified):
//   field0 [ 0:16) w unsigned, scale 1024 ; field1..3 signed, scale 256
constexpr float W_SCALE = 1024.0f;
constexpr float V_SCALE = 256.0f;

// Destination-ownership tiling.
// NEAR source: |fx|<=63 && |fy|<=63  -> handled in LDS by the owning tile(s).
//   (|f|<=63 => corner cells within +-64 of source, so a 64-px scan margin
//    around the owned tile covers every near contribution exactly.)
// FAR source: anything else (~0.3% for sigma=20 flow) -> verified global-atomic
//   path, ordered before the tile kernels on the stream.
constexpr int   TILE = 128;
constexpr int   MARG = 64;
constexpr float NEAR_TH = 63.0f;
constexpr int   REG  = TILE + 2 * MARG;        // 256-wide scan region
constexpr int   TX   = W / TILE;               // 15
constexpr int   TY   = (H + TILE - 1) / TILE;  // 9 (last tile row: 56 px)
constexpr int   NTILES = B * TX * TY;          // 540

struct Splat {
    bool  valid;
    int   di;
    float df;
    float k[4];
    int   cx[4], cy[4];
};

// Identical arithmetic everywhere (matches the verified baseline kernels).
__device__ __forceinline__ Splat make_splat(int x, int y, float fx, float fy) {
    Splat s;
    float xd = (float)x + fx;
    float yd = (float)y + fy;
    float xf = floorf(xd), yf = floorf(yd);
    int xfi = (int)xf, yfi = (int)yf;
    int xci = xfi + 1, yci = yfi + 1;
    s.valid = (xfi >= 0) & (xci <= W) & (yfi >= 0) & (yci <= H);
    s.di = (int)(100.0f * sqrtf(fx * fx + fy * fy));
    s.df = (float)s.di;
    float wx1 = xd - xf, wx0 = (xf + 1.0f) - xd;
    float wy1 = yd - yf, wy0 = (yf + 1.0f) - yd;
    int x0 = min(max(xfi, 0), W - 1), x1 = min(max(xci, 0), W - 1);
    int y0 = min(max(yfi, 0), H - 1), y1 = min(max(yci, 0), H - 1);
    s.k[0] = wx0 * wy0; s.cx[0] = x0; s.cy[0] = y0;
    s.k[1] = wx1 * wy0; s.cx[1] = x1; s.cy[1] = y0;
    s.k[2] = wx0 * wy1; s.cx[2] = x0; s.cy[2] = y1;
    s.k[3] = wx1 * wy1; s.cx[3] = x1; s.cy[3] = y1;
    return s;
}

__device__ __forceinline__ bool is_near(float fx, float fy) {
    return (fabsf(fx) <= NEAR_TH) && (fabsf(fy) <= NEAR_TH);
}

// ---------------------------------------------------------------------------
// K1: far sources only — global scatter-max depth (rare: ~0.3% of sources)
// ---------------------------------------------------------------------------
__global__ void far_depth(const float* __restrict__ flow, int* __restrict__ dbuf) {
    int n = blockIdx.x * blockDim.x + threadIdx.x;
    if (n >= N) return;
    float2 f = reinterpret_cast<const float2*>(flow)[n];
    if (is_near(f.x, f.y)) return;
    int b   = n / HW;
    int pix = n - b * HW;
    int y   = pix / W;
    int x   = pix - y * W;
    Splat s = make_splat(x, y, f.x, f.y);
    if (!s.valid) return;
    int base = b * HW;
    #pragma unroll
    for (int c = 0; c < 4; ++c)
        if (s.k[c] >= 0.25f)
            atomicMax(&dbuf[base + s.cy[c] * W + s.cx[c]], s.di);
}

// ---------------------------------------------------------------------------
// K2: tile depth — scatter-max in LDS, exclusive-ownership merge (no atomics)
// ---------------------------------------------------------------------------
__global__ __launch_bounds__(1024, 8) void tile_depth(const float* __restrict__ flow,
                                                      int* __restrict__ dbuf) {
    __shared__ int dloc[TILE * TILE];            // 64 KB -> 2 WG/CU
    const int t = threadIdx.x;
    for (int i = t; i < TILE * TILE; i += 1024) dloc[i] = 0;
    __syncthreads();

    int tile = blockIdx.x;
    int txi  = tile % TX;
    int tmp  = tile / TX;
    int tyi  = tmp % TY;
    int b    = tmp / TY;
    int x0 = txi * TILE, y0 = tyi * TILE;
    int base = b * HW;

    int rx  = t & (REG - 1);                     // 256-wide region: 1 col/thread
    int gx  = x0 - MARG + rx;
    int ty4 = t >> 8;                            // 4 rows in flight
    if (gx >= 0 && gx < W) {
        for (int ry = ty4; ry < REG; ry += 4) {
            int gy = y0 - MARG + ry;
            if (gy < 0 || gy >= H) continue;
            float2 f = reinterpret_cast<const float2*>(flow)[base + gy * W + gx];
            if (!is_near(f.x, f.y)) continue;    // far handled globally (idempotent max)
            Splat s = make_splat(gx, gy, f.x, f.y);
            if (!s.valid) continue;
            #pragma unroll
            for (int c = 0; c < 4; ++c) {
                int cx = s.cx[c], cy = s.cy[c];
                if (s.k[c] >= 0.25f &&
                    cx >= x0 && cx < x0 + TILE && cy >= y0 && cy < y0 + TILE)
                    atomicMax(&dloc[(cy - y0) * TILE + (cx - x0)], s.di);
            }
        }
    }
    __syncthreads();

    // Exclusive ownership: plain read-max-write (far_depth already complete).
    int oh = min(TILE, H - y0);
    for (int i = t; i < TILE * TILE; i += 1024) {
        int ly = i >> 7, lx = i & (TILE - 1);
        if (ly >= oh) continue;
        int g = base + (y0 + ly) * W + (x0 + lx);
        int v = dloc[i];
        if (v > dbuf[g]) dbuf[g] = v;
    }
}

// ---------------------------------------------------------------------------
// K3: far sources only — z-tested global u64 splat (rare)
// ---------------------------------------------------------------------------
__global__ void far_splat(const float* __restrict__ im0,
                          const float* __restrict__ flow,
                          const int* __restrict__ dbuf,
                          unsigned long long* __restrict__ acc) {
    int n = blockIdx.x * blockDim.x + threadIdx.x;
    if (n >= N) return;
    float2 f = reinterpret_cast<const float2*>(flow)[n];
    if (is_near(f.x, f.y)) return;               // exact complement of tile path
    int b   = n / HW;
    int pix = n - b * HW;
    int y   = pix / W;
    int x   = pix - y * W;
    Splat s = make_splat(x, y, f.x, f.y);
    if (!s.valid) return;
    float v0 = im0[(b * C + 0) * HW + pix];
    float v1 = im0[(b * C + 1) * HW + pix];
    float v2 = im0[(b * C + 2) * HW + pix];
    int base = b * HW;
    #pragma unroll
    for (int c = 0; c < 4; ++c) {
        if (s.k[c] < 0.25f) continue;
        int idx = base + s.cy[c] * W + s.cx[c];
        float dg = (float)dbuf[idx];
        if (dg - s.df <= MOTION_TH) {
            float k = s.k[c];
            long long wq = (long long)__float2int_rn(k * W_SCALE);
            long long rq = (long long)__float2int_rn(v0 * k * V_SCALE);
            long long gq = (long long)__float2int_rn(v1 * k * V_SCALE);
            long long bq = (long long)__float2int_rn(v2 * k * V_SCALE);
            long long S  = wq + (rq << 16) + (gq << 32) + (bq << 48);
            atomicAdd(&acc[idx], (unsigned long long)S);
        }
    }
}

// ---------------------------------------------------------------------------
// K4: tile splat — LDS u64 accumulation + fused normalize/write (owned cells)
// ---------------------------------------------------------------------------
__global__ __launch_bounds__(1024, 4) void tile_splat(const float* __restrict__ im0,
                                                      const float* __restrict__ flow,
                                                      const int* __restrict__ dbuf,
                                                      const unsigned long long* __restrict__ acc,
                                                      float* __restrict__ out) {
    __shared__ unsigned long long aloc[TILE * TILE];   // 128 KB -> 1 WG/CU, 16 waves
    const int t = threadIdx.x;
    for (int i = t; i < TILE * TILE; i += 1024) aloc[i] = 0ull;
    __syncthreads();

    int tile = blockIdx.x;
    int txi  = tile % TX;
    int tmp  = tile / TX;
    int tyi  = tmp % TY;
    int b    = tmp / TY;
    int x0 = txi * TILE, y0 = tyi * TILE;
    int base = b * HW;

    int rx  = t & (REG - 1);
    int gx  = x0 - MARG + rx;
    int ty4 = t >> 8;
    if (gx >= 0 && gx < W) {
        for (int ry = ty4; ry < REG; ry += 4) {
            int gy = y0 - MARG + ry;
            if (gy < 0 || gy >= H) continue;
            int pix = gy * W + gx;
            float2 f = reinterpret_cast<const float2*>(flow)[base + pix];
            if (!is_near(f.x, f.y)) continue;    // disjoint from far_splat
            Splat s = make_splat(gx, gy, f.x, f.y);
            if (!s.valid) continue;

            // Decide owned+passing corners first (dbuf reads hit L1/L2: the
            // owned tile's 64 KB depth slab is this CU's hot set).
            bool go[4]; int lidx[4]; bool any = false;
            #pragma unroll
            for (int c = 0; c < 4; ++c) {
                int cx = s.cx[c], cy = s.cy[c];
                bool o = (s.k[c] >= 0.25f) & (cx >= x0) & (cx < x0 + TILE)
                       & (cy >= y0) & (cy < y0 + TILE);
                if (o) {
                    float dg = (float)dbuf[base + cy * W + cx];
                    o = (dg - s.df <= MOTION_TH);
                }
                go[c]   = o;
                lidx[c] = (cy - y0) * TILE + (cx - x0);
                any |= o;
            }
            if (!any) continue;
            float v0 = im0[(b * C + 0) * HW + pix];
            float v1 = im0[(b * C + 1) * HW + pix];
            float v2 = im0[(b * C + 2) * HW + pix];
            #pragma unroll
            for (int c = 0; c < 4; ++c) {
                if (!go[c]) continue;
                float k = s.k[c];
                long long wq = (long long)__float2int_rn(k * W_SCALE);
                long long rq = (long long)__float2int_rn(v0 * k * V_SCALE);
                long long gq = (long long)__float2int_rn(v1 * k * V_SCALE);
                long long bq = (long long)__float2int_rn(v2 * k * V_SCALE);
                unsigned long long S =
                    (unsigned long long)(wq + (rq << 16) + (gq << 32) + (bq << 48));
                atomicAdd(&aloc[lidx[c]], S);
            }
        }
    }
    __syncthreads();

    // Fused merge (far contributions from global acc) + decode + normalize.
    int oh = min(TILE, H - y0);
    for (int i = t; i < TILE * TILE; i += 1024) {
        int ly = i >> 7, lx = i & (TILE - 1);
        if (ly >= oh) continue;
        int cell = (y0 + ly) * W + (x0 + lx);
        long long T64 = (long long)(aloc[i] + acc[base + cell]);

        int wq = (int)(T64 & 0xffff);
        long long T1 = (T64 - wq) >> 16;
        int rq = (int)(((T1 & 0xffff) ^ 0x8000) - 0x8000);
        long long T2 = (T1 - rq) >> 16;
        int gq = (int)(((T2 & 0xffff) ^ 0x8000) - 0x8000);
        long long T3 = (T2 - gq) >> 16;
        int bq = (int)T3;

        float w  = (float)wq * (1.0f / W_SCALE);
        float r  = (float)rq * (1.0f / V_SCALE);
        float g  = (float)gq * (1.0f / V_SCALE);
        float bl = (float)bq * (1.0f / V_SCALE);

        float den = fmaxf(w * (1.0f / 3.0f), EPS);
        float inv = 1.0f / den;
        float* p = out + (size_t)b * C * HW + cell;
        p[0]      = r  * inv;
        p[HW]     = g  * inv;
        p[2 * HW] = bl * inv;
    }
}

extern "C" void kernel_launch(void* const* d_in, const int* in_sizes, int n_in,
                              void* d_out, int out_size, void* d_ws, size_t ws_size,
                              hipStream_t stream) {
    const float* im0  = (const float*)d_in[0];
    const float* flow = (const float*)d_in[1];
    float* out = (float*)d_out;

    unsigned long long* acc = (unsigned long long*)d_ws;      // N x 8B (far sums)
    int* dbuf = (int*)((char*)d_ws + (size_t)N * 8);          // N x 4B

    (void)hipMemsetAsync(d_ws, 0, (size_t)N * 12, stream);

    const int block = 256;
    const int grid  = (N + block - 1) / block;

    // Stream order gives the required phase ordering:
    // far depth -> tile depth (reads far results) -> far splat (reads final
    // dbuf) -> tile splat (reads final dbuf + far acc, writes out).
    far_depth <<<grid,   block, 0, stream>>>(flow, dbuf);
    tile_depth<<<NTILES, 1024,  0, stream>>>(flow, dbuf);
    far_splat <<<grid,   block, 0, stream>>>(im0, flow, dbuf, acc);
    tile_splat<<<NTILES, 1024,  0, stream>>>(im0, flow, dbuf, acc, out);
}

// Round 2
// 518.881 us; speedup vs baseline: 1.8430x; 1.3055x over previous
//
#include <hip/hip_runtime.h>

// Problem constants (fixed by setup_inputs)
constexpr int B = 4, C = 3, H = 1080, W = 1920;
constexpr int HW = H * W;
constexpr int N = B * HW;                 // 8,294,400 source pixels
constexpr float MOTION_TH = 25.0f;        // 0.25 * 100
constexpr float EPS = 1e-5f;

// Packed fixed-point accumulator (verified in prior rounds):
//   field0 [ 0:16) w unsigned, scale 1024 ; field1..3 signed, scale 256
constexpr float W_SCALE = 1024.0f;
constexpr float V_SCALE = 256.0f;

// Destination-ownership tiling, fused depth+splat.
//   NEAR source: |fx|<=47 && |fy|<=47  -> LDS path in the owning tile.
//   FAR  source: else (~3.7% of N(0,20) flow) -> global-atomic path.
// Tile 160x44 owned cells; scan region 256x140 (margin 48).
// LDS: acc u64 (55 KB) + depth u16 (14 KB) = 70.4 KB -> 2 WG/CU, 8 waves/SIMD.
// Depth scan stages i32 in the (not-yet-zeroed) acc region.
constexpr int   TILE_W = 160, TILE_H = 44;
constexpr int   MARG   = 48;
constexpr float NEAR_TH = 47.0f;
constexpr int   REG_W  = TILE_W + 2 * MARG;        // 256 (pow2 thread mapping)
constexpr int   REG_H  = TILE_H + 2 * MARG;        // 140
constexpr int   CELLS  = TILE_W * TILE_H;          // 7040
constexpr int   TX = W / TILE_W;                   // 12
constexpr int   TY = (H + TILE_H - 1) / TILE_H;    // 25 (last tile: 24 rows)
constexpr int   NTILES = B * TX * TY;              // 1200

struct Splat {
    bool  valid;
    int   di;
    float df;
    float k[4];
    int   cx[4], cy[4];
};

// Identical arithmetic to the verified baseline.
__device__ __forceinline__ Splat make_splat(int x, int y, float fx, float fy) {
    Splat s;
    float xd = (float)x + fx;
    float yd = (float)y + fy;
    float xf = floorf(xd), yf = floorf(yd);
    int xfi = (int)xf, yfi = (int)yf;
    int xci = xfi + 1, yci = yfi + 1;
    s.valid = (xfi >= 0) & (xci <= W) & (yfi >= 0) & (yci <= H);
    s.di = (int)(100.0f * sqrtf(fx * fx + fy * fy));
    s.df = (float)s.di;
    float wx1 = xd - xf, wx0 = (xf + 1.0f) - xd;
    float wy1 = yd - yf, wy0 = (yf + 1.0f) - yd;
    int x0 = min(max(xfi, 0), W - 1), x1 = min(max(xci, 0), W - 1);
    int y0 = min(max(yfi, 0), H - 1), y1 = min(max(yci, 0), H - 1);
    s.k[0] = wx0 * wy0; s.cx[0] = x0; s.cy[0] = y0;
    s.k[1] = wx1 * wy0; s.cx[1] = x1; s.cy[1] = y0;
    s.k[2] = wx0 * wy1; s.cx[2] = x0; s.cy[2] = y1;
    s.k[3] = wx1 * wy1; s.cx[3] = x1; s.cy[3] = y1;
    return s;
}

__device__ __forceinline__ bool is_near(float fx, float fy) {
    return (fabsf(fx) <= NEAR_TH) && (fabsf(fy) <= NEAR_TH);
}

// ---------------------------------------------------------------------------
// K1: far sources only — global scatter-max depth
// ---------------------------------------------------------------------------
__global__ void far_depth(const float* __restrict__ flow, int* __restrict__ dbuf) {
    int n = blockIdx.x * blockDim.x + threadIdx.x;
    if (n >= N) return;
    float2 f = reinterpret_cast<const float2*>(flow)[n];
    if (is_near(f.x, f.y)) return;
    int b   = n / HW;
    int pix = n - b * HW;
    int y   = pix / W;
    int x   = pix - y * W;
    Splat s = make_splat(x, y, f.x, f.y);
    if (!s.valid) return;
    int base = b * HW;
    #pragma unroll
    for (int c = 0; c < 4; ++c)
        if (s.k[c] >= 0.25f)
            atomicMax(&dbuf[base + s.cy[c] * W + s.cx[c]], s.di);
}

// ---------------------------------------------------------------------------
// K2: fused tile depth + splat.
//   Phase A: LDS scatter-max depth (i32 staged inside acc region)
//   Phase B: merge far depth from dbuf, write final dbuf, stash u16 depth
//   Phase C: zero LDS acc
//   Phase D: re-scan region, z-test vs LDS u16 depth, LDS u64 accumulate
//   Phase E: plain-store owned acc cells to global (exclusive ownership)
// ---------------------------------------------------------------------------
__global__ __launch_bounds__(1024, 8) void tile_fused(
        const float* __restrict__ im0,
        const float* __restrict__ flow,
        int* __restrict__ dbuf,
        unsigned long long* __restrict__ acc) {
    __shared__ unsigned long long aloc[CELLS];   // 56320 B
    __shared__ unsigned short     du16[CELLS];   // 14080 B (total 70400 B)
    int* dstage = (int*)aloc;                    // CELLS i32 in low half of aloc

    const int t = threadIdx.x;
    int tile = blockIdx.x;
    int txi  = tile % TX;
    int tmp  = tile / TX;
    int tyi  = tmp % TY;
    int b    = tmp / TY;
    int x0 = txi * TILE_W, y0 = tyi * TILE_H;
    int base = b * HW;
    const float2* flow2 = reinterpret_cast<const float2*>(flow);

    for (int i = t; i < CELLS; i += 1024) dstage[i] = 0;
    __syncthreads();

    // Thread -> (column, row-phase) mapping over the 256-wide region.
    int rxc = t & (REG_W - 1);
    int gx  = x0 - MARG + rxc;
    bool colok = (gx >= 0) & (gx < W);
    int gy_hi = min(H, y0 + TILE_H + MARG);
    int gys = y0 - MARG + (t >> 8);
    if (gys < 0) gys += (-gys + 3) & ~3;         // stay on phase mod 4, >= 0

    // ---- Phase A: depth scan ----
    if (colok) {
        const float2* fp = flow2 + base + (long)gys * W + gx;
        float2 fnext = (gys < gy_hi) ? *fp : float2{0.0f, 0.0f};
        for (int gy = gys; gy < gy_hi; gy += 4, fp += 4 * W) {
            float2 f = fnext;
            if (gy + 4 < gy_hi) fnext = fp[4 * W];   // prefetch next row
            if (!is_near(f.x, f.y)) continue;
            Splat s = make_splat(gx, gy, f.x, f.y);
            if (!s.valid) continue;
            #pragma unroll
            for (int c = 0; c < 4; ++c) {
                int lx = s.cx[c] - x0, ly = s.cy[c] - y0;
                if (s.k[c] >= 0.25f &&
                    (unsigned)lx < (unsigned)TILE_W && (unsigned)ly < (unsigned)TILE_H)
                    atomicMax(&dstage[ly * TILE_W + lx], s.di);
            }
        }
    }
    __syncthreads();

    // ---- Phase B: merge far depth, write dbuf + du16 ----
    int oh = min(TILE_H, H - y0);
    for (int i = t; i < CELLS; i += 1024) {
        int ly = i / TILE_W, lx = i - ly * TILE_W;
        int dn = dstage[i];
        unsigned short dv = 0;
        if (ly < oh) {
            int g = base + (y0 + ly) * W + (x0 + lx);
            int dm = max(dn, dbuf[g]);           // far_depth already complete
            dbuf[g] = dm;                        // final depth for far_splat
            dv = (unsigned short)min(dm, 65535); // clamp safe: near df <= 8909
        }
        du16[i] = dv;                            // disjoint from dstage reads
    }
    __syncthreads();                             // all dstage reads done

    // ---- Phase C: zero acc (clobbers dstage) ----
    for (int i = t; i < CELLS; i += 1024) aloc[i] = 0ull;
    __syncthreads();

    // ---- Phase D: splat scan, z-test in LDS ----
    if (colok) {
        const float2* fp = flow2 + base + (long)gys * W + gx;
        float2 fnext = (gys < gy_hi) ? *fp : float2{0.0f, 0.0f};
        for (int gy = gys; gy < gy_hi; gy += 4, fp += 4 * W) {
            float2 f = fnext;
            if (gy + 4 < gy_hi) fnext = fp[4 * W];
            if (!is_near(f.x, f.y)) continue;
            Splat s = make_splat(gx, gy, f.x, f.y);
            if (!s.valid) continue;

            bool go[4]; int lidx[4]; bool any = false;
            #pragma unroll
            for (int c = 0; c < 4; ++c) {
                int lx = s.cx[c] - x0, ly = s.cy[c] - y0;
                bool o = (s.k[c] >= 0.25f) &
                         ((unsigned)lx < (unsigned)TILE_W) &
                         ((unsigned)ly < (unsigned)TILE_H);
                lidx[c] = ly * TILE_W + lx;
                if (o) {
                    float dg = (float)du16[lidx[c]];
                    o = (dg - s.df <= MOTION_TH);
                }
                go[c] = o; any |= o;
            }
            if (!any) continue;
            int pix = gy * W + gx;
            float v0 = im0[(b * C + 0) * HW + pix];
            float v1 = im0[(b * C + 1) * HW + pix];
            float v2 = im0[(b * C + 2) * HW + pix];
            #pragma unroll
            for (int c = 0; c < 4; ++c) {
                if (!go[c]) continue;
                float k = s.k[c];
                long long wq = (long long)__float2int_rn(k * W_SCALE);
                long long rq = (long long)__float2int_rn(v0 * k * V_SCALE);
                long long gq = (long long)__float2int_rn(v1 * k * V_SCALE);
                long long bq = (long long)__float2int_rn(v2 * k * V_SCALE);
                unsigned long long S =
                    (unsigned long long)(wq + (rq << 16) + (gq << 32) + (bq << 48));
                atomicAdd(&aloc[lidx[c]], S);
            }
        }
    }
    __syncthreads();

    // ---- Phase E: plain-store owned cells (before far_splat adds) ----
    for (int i = t; i < CELLS; i += 1024) {
        int ly = i / TILE_W, lx = i - ly * TILE_W;
        if (ly < oh)
            acc[base + (y0 + ly) * W + (x0 + lx)] = aloc[i];
    }
}

// ---------------------------------------------------------------------------
// K3: far sources only — z-tested global u64 splat (reads final dbuf)
// ---------------------------------------------------------------------------
__global__ void far_splat(const float* __restrict__ im0,
                          const float* __restrict__ flow,
                          const int* __restrict__ dbuf,
                          unsigned long long* __restrict__ acc) {
    int n = blockIdx.x * blockDim.x + threadIdx.x;
    if (n >= N) return;
    float2 f = reinterpret_cast<const float2*>(flow)[n];
    if (is_near(f.x, f.y)) return;               // exact complement of tile path
    int b   = n / HW;
    int pix = n - b * HW;
    int y   = pix / W;
    int x   = pix - y * W;
    Splat s = make_splat(x, y, f.x, f.y);
    if (!s.valid) return;
    float v0 = im0[(b * C + 0) * HW + pix];
    float v1 = im0[(b * C + 1) * HW + pix];
    float v2 = im0[(b * C + 2) * HW + pix];
    int base = b * HW;
    #pragma unroll
    for (int c = 0; c < 4; ++c) {
        if (s.k[c] < 0.25f) continue;
        int idx = base + s.cy[c] * W + s.cx[c];
        float dg = (float)dbuf[idx];
        if (dg - s.df <= MOTION_TH) {
            float k = s.k[c];
            long long wq = (long long)__float2int_rn(k * W_SCALE);
            long long rq = (long long)__float2int_rn(v0 * k * V_SCALE);
            long long gq = (long long)__float2int_rn(v1 * k * V_SCALE);
            long long bq = (long long)__float2int_rn(v2 * k * V_SCALE);
            long long S  = wq + (rq << 16) + (gq << 32) + (bq << 48);
            atomicAdd(&acc[idx], (unsigned long long)S);
        }
    }
}

// ---------------------------------------------------------------------------
// K4: decode fields, out[c] = v[c] / max(w / C, eps)  (verified round-0 code)
// ---------------------------------------------------------------------------
__global__ void norm_pass(const unsigned long long* __restrict__ acc,
                          float* __restrict__ out) {
    int n = blockIdx.x * blockDim.x + threadIdx.x;
    if (n >= N) return;
    int b   = n / HW;
    int pix = n - b * HW;

    long long T = (long long)acc[n];
    int wq = (int)(T & 0xffff);
    long long T1 = (T - wq) >> 16;
    int rq = (int)(((T1 & 0xffff) ^ 0x8000) - 0x8000);
    long long T2 = (T1 - rq) >> 16;
    int gq = (int)(((T2 & 0xffff) ^ 0x8000) - 0x8000);
    long long T3 = (T2 - gq) >> 16;
    int bq = (int)T3;

    float w  = (float)wq * (1.0f / W_SCALE);
    float r  = (float)rq * (1.0f / V_SCALE);
    float g  = (float)gq * (1.0f / V_SCALE);
    float bl = (float)bq * (1.0f / V_SCALE);

    float den = fmaxf(w * (1.0f / 3.0f), EPS);
    float inv = 1.0f / den;
    float* p = out + (size_t)b * C * HW + pix;
    p[0]      = r  * inv;
    p[HW]     = g  * inv;
    p[2 * HW] = bl * inv;
}

extern "C" void kernel_launch(void* const* d_in, const int* in_sizes, int n_in,
                              void* d_out, int out_size, void* d_ws, size_t ws_size,
                              hipStream_t stream) {
    const float* im0  = (const float*)d_in[0];
    const float* flow = (const float*)d_in[1];
    float* out = (float*)d_out;

    unsigned long long* acc = (unsigned long long*)d_ws;      // N x 8B
    int* dbuf = (int*)((char*)d_ws + (size_t)N * 8);          // N x 4B

    (void)hipMemsetAsync(d_ws, 0, (size_t)N * 12, stream);

    const int block = 256;
    const int grid  = (N + block - 1) / block;

    // Ordering: far depth -> fused tiles (merge far depth, write final dbuf,
    // near splat, plain-store acc) -> far splat (atomics into acc) -> norm.
    far_depth <<<grid,   block, 0, stream>>>(flow, dbuf);
    tile_fused<<<NTILES, 1024,  0, stream>>>(im0, flow, dbuf, acc);
    far_splat <<<grid,   block, 0, stream>>>(im0, flow, dbuf, acc);
    norm_pass <<<grid,   block, 0, stream>>>(acc, out);
}

// Round 3
// 397.526 us; speedup vs baseline: 2.4056x; 1.3053x over previous
//
#include <hip/hip_runtime.h>

// Problem constants (fixed by setup_inputs)
constexpr int B = 4, C = 3, H = 1080, W = 1920;
constexpr int HW = H * W;
constexpr int N = B * HW;                 // 8,294,400 source pixels
constexpr float MOTION_TH = 25.0f;        // 0.25 * 100
constexpr float EPS = 1e-5f;

// Packed fixed-point accumulator (verified):
//   field0 [ 0:16) w unsigned, scale 1024 ; field1..3 signed, scale 256
constexpr float W_SCALE = 1024.0f;
constexpr float V_SCALE = 256.0f;

// Destination-ownership tiling, fused depth+splat with worklist compaction.
//   NEAR source: |fx|<=47 && |fy|<=47  -> LDS path in the owning tile.
//   FAR  source: else (~3.7%)          -> global-atomic path.
// Tile 160x36 (exact 12x30 grid, no partial tiles); scan region 256x132.
// LDS: acc u64 45K + depth u16 11.25K + worklist u16 18K = 74.3KB -> 2 WG/CU.
constexpr int   TILE_W = 160, TILE_H = 36;
constexpr int   MARG   = 48;
constexpr float NEAR_TH = 47.0f;
constexpr int   REG_W  = TILE_W + 2 * MARG;        // 256 (pow2 col mapping)
constexpr int   REG_H  = TILE_H + 2 * MARG;        // 132
constexpr int   CELLS  = TILE_W * TILE_H;          // 5760
constexpr int   TX = W / TILE_W;                   // 12 (exact)
constexpr int   TY = H / TILE_H;                   // 30 (exact)
constexpr int   NTILES = B * TX * TY;              // 1440 (divisible by 8)
constexpr int   WL_CAP = 9216;                     // expected ~6156 +- 80

struct Splat {
    bool  valid;
    int   di;
    float df;
    float k[4];
    int   cx[4], cy[4];
};

// Identical arithmetic to the verified baseline (used by far kernels).
__device__ __forceinline__ Splat make_splat(int x, int y, float fx, float fy) {
    Splat s;
    float xd = (float)x + fx;
    float yd = (float)y + fy;
    float xf = floorf(xd), yf = floorf(yd);
    int xfi = (int)xf, yfi = (int)yf;
    int xci = xfi + 1, yci = yfi + 1;
    s.valid = (xfi >= 0) & (xci <= W) & (yfi >= 0) & (yci <= H);
    s.di = (int)(100.0f * sqrtf(fx * fx + fy * fy));
    s.df = (float)s.di;
    float wx1 = xd - xf, wx0 = (xf + 1.0f) - xd;
    float wy1 = yd - yf, wy0 = (yf + 1.0f) - yd;
    int x0 = min(max(xfi, 0), W - 1), x1 = min(max(xci, 0), W - 1);
    int y0 = min(max(yfi, 0), H - 1), y1 = min(max(yci, 0), H - 1);
    s.k[0] = wx0 * wy0; s.cx[0] = x0; s.cy[0] = y0;
    s.k[1] = wx1 * wy0; s.cx[1] = x1; s.cy[1] = y0;
    s.k[2] = wx0 * wy1; s.cx[2] = x0; s.cy[2] = y1;
    s.k[3] = wx1 * wy1; s.cx[3] = x1; s.cy[3] = y1;
    return s;
}

__device__ __forceinline__ bool is_near(float fx, float fy) {
    return (fabsf(fx) <= NEAR_TH) && (fabsf(fy) <= NEAR_TH);
}

// ---------------------------------------------------------------------------
// K1: far sources only — global scatter-max depth
// ---------------------------------------------------------------------------
__global__ void far_depth(const float* __restrict__ flow, int* __restrict__ dbuf) {
    int n = blockIdx.x * blockDim.x + threadIdx.x;
    if (n >= N) return;
    float2 f = reinterpret_cast<const float2*>(flow)[n];
    if (is_near(f.x, f.y)) return;
    int b   = n / HW;
    int pix = n - b * HW;
    int y   = pix / W;
    int x   = pix - y * W;
    Splat s = make_splat(x, y, f.x, f.y);
    if (!s.valid) return;
    int base = b * HW;
    #pragma unroll
    for (int c = 0; c < 4; ++c)
        if (s.k[c] >= 0.25f)
            atomicMax(&dbuf[base + s.cy[c] * W + s.cx[c]], s.di);
}

// ---------------------------------------------------------------------------
// K2: fused tile kernel with worklist compaction.
//   A0: cheap bbox+near scan of the region -> wave-compacted LDS worklist
//   A1: replay worklist: geometry + LDS scatter-max depth (i32 in acc region)
//   B : merge far depth from dbuf -> write final dbuf + du16
//   C : zero LDS acc
//   D : replay worklist: geometry + z-test vs du16 + LDS u64 accumulate
//   E : plain-store owned acc cells (exclusive ownership)
// ---------------------------------------------------------------------------
__global__ __launch_bounds__(1024, 8) void tile_fused(
        const float* __restrict__ im0,
        const float* __restrict__ flow,
        int* __restrict__ dbuf,
        unsigned long long* __restrict__ acc) {
    __shared__ unsigned long long aloc[CELLS];     // 46080 B
    __shared__ unsigned short     du16[CELLS];     // 11520 B
    __shared__ unsigned short     wl[WL_CAP];      // 18432 B  (total 76036)
    __shared__ int                wl_cnt;
    int* dstage = (int*)aloc;                      // CELLS i32, low half of aloc

    const int t = threadIdx.x;
    // XCD-chunk swizzle: 1440 tiles / 8 XCDs = 180 contiguous tiles per XCD.
    int tile = (blockIdx.x & 7) * (NTILES / 8) + (blockIdx.x >> 3);
    int txi  = tile % TX;
    int tmp  = tile / TX;
    int tyi  = tmp % TY;
    int b    = tmp / TY;
    const int x0t = txi * TILE_W, y0t = tyi * TILE_H;
    const int base = b * HW;
    const float2* flow2 = reinterpret_cast<const float2*>(flow);

    if (t == 0) wl_cnt = 0;
    for (int i = t; i < CELLS; i += 1024) dstage[i] = 0;
    __syncthreads();

    // Thread -> (column, row-phase) mapping over the 256-wide region.
    const int   rxc   = t & (REG_W - 1);
    const int   gx    = x0t - MARG + rxc;
    const bool  colok = (gx >= 0) & (gx < W);
    const int   gy_hi = min(H, y0t + TILE_H + MARG);
    int gys = y0t - MARG + (t >> 8);
    if (gys < 0) gys += (-gys + 3) & ~3;           // stay on phase mod 4, >= 0
    const float gxf  = (float)gx;
    const float bxlo = (float)(x0t - 1),    bxhi = (float)(x0t + TILE_W);
    const float bylo = (float)(y0t - 1),    byhi = (float)(y0t + TILE_H);
    const int   lane = t & 63;

    // ---- Phase A0: bbox scan + wave-compacted worklist append ----
    if (colok) {
        const float2* fp = flow2 + base + (long)gys * W + gx;
        float2 fnext = (gys < gy_hi) ? *fp : float2{0.0f, 0.0f};
        for (int gy = gys; gy < gy_hi; gy += 4, fp += 4 * W) {
            float2 f = fnext;
            if (gy + 4 < gy_hi) fnext = fp[4 * W];
            float xd = gxf + f.x;
            float yd = (float)gy + f.y;
            bool hit = (xd >= bxlo) & (xd < bxhi) & (yd >= bylo) & (yd < byhi)
                     & (fabsf(f.x) <= NEAR_TH) & (fabsf(f.y) <= NEAR_TH);
            unsigned long long m = __ballot(hit);
            if (hit) {
                int rank = __popcll(m & ((1ull << lane) - 1ull));
                int bslot = 0;
                if (rank == 0) bslot = atomicAdd(&wl_cnt, __popcll(m));
                bslot = __shfl(bslot, __ffsll((long long)m) - 1);
                int slot = bslot + rank;
                if (slot < WL_CAP)
                    wl[slot] = (unsigned short)(((gy - (y0t - MARG)) << 8) | rxc);
            }
        }
    }
    __syncthreads();
    const int cnt = min(wl_cnt, WL_CAP);

    // ---- Phase A1: replay worklist -> LDS depth max ----
    for (int w = t; w < cnt; w += 1024) {
        int e  = wl[w];
        int rx = e & 255, ry = e >> 8;
        int gx2 = x0t - MARG + rx, gy2 = y0t - MARG + ry;
        float2 f = flow2[base + gy2 * W + gx2];
        float xd = (float)gx2 + f.x, yd = (float)gy2 + f.y;
        float xf = floorf(xd), yf = floorf(yd);
        int xfi = (int)xf, yfi = (int)yf;
        int xci = xfi + 1, yci = yfi + 1;
        if (!((xfi >= 0) & (xci <= W) & (yfi >= 0) & (yci <= H))) continue;
        float wx1 = xd - xf, wx0 = (xf + 1.0f) - xd;
        float wy1 = yd - yf, wy0 = (yf + 1.0f) - yd;
        int X0 = min(max(xfi, 0), W - 1), X1 = min(max(xci, 0), W - 1);
        int Y0 = min(max(yfi, 0), H - 1), Y1 = min(max(yci, 0), H - 1);
        int lx0 = X0 - x0t, lx1 = X1 - x0t, ly0 = Y0 - y0t, ly1 = Y1 - y0t;
        bool ox0 = (unsigned)lx0 < (unsigned)TILE_W;
        bool ox1 = (unsigned)lx1 < (unsigned)TILE_W;
        bool oy0 = (unsigned)ly0 < (unsigned)TILE_H;
        bool oy1 = (unsigned)ly1 < (unsigned)TILE_H;
        float k0 = wx0 * wy0, k1 = wx1 * wy0, k2 = wx0 * wy1, k3 = wx1 * wy1;
        bool m0 = (k0 >= 0.25f) & ox0 & oy0;
        bool m1 = (k1 >= 0.25f) & ox1 & oy0;
        bool m2 = (k2 >= 0.25f) & ox0 & oy1;
        bool m3 = (k3 >= 0.25f) & ox1 & oy1;
        if (!(m0 | m1 | m2 | m3)) continue;
        int di = (int)(100.0f * sqrtf(f.x * f.x + f.y * f.y));
        if (m0) atomicMax(&dstage[ly0 * TILE_W + lx0], di);
        if (m1) atomicMax(&dstage[ly0 * TILE_W + lx1], di);
        if (m2) atomicMax(&dstage[ly1 * TILE_W + lx0], di);
        if (m3) atomicMax(&dstage[ly1 * TILE_W + lx1], di);
    }
    __syncthreads();

    // ---- Phase B: merge far depth, write final dbuf + du16 ----
    for (int i = t; i < CELLS; i += 1024) {
        int ly = i / TILE_W, lx = i - ly * TILE_W;
        int g  = base + (y0t + ly) * W + (x0t + lx);
        int dm = max(dstage[i], dbuf[g]);          // far_depth already complete
        dbuf[g] = dm;                              // final depth for far_splat
        du16[i] = (unsigned short)min(dm, 65535);
    }
    __syncthreads();                               // dstage reads done

    // ---- Phase C: zero acc (clobbers dstage) ----
    for (int i = t; i < CELLS; i += 1024) aloc[i] = 0ull;
    __syncthreads();

    // ---- Phase D: replay worklist -> z-test + LDS u64 accumulate ----
    for (int w = t; w < cnt; w += 1024) {
        int e  = wl[w];
        int rx = e & 255, ry = e >> 8;
        int gx2 = x0t - MARG + rx, gy2 = y0t - MARG + ry;
        int pix = gy2 * W + gx2;
        float2 f = flow2[base + pix];
        float xd = (float)gx2 + f.x, yd = (float)gy2 + f.y;
        float xf = floorf(xd), yf = floorf(yd);
        int xfi = (int)xf, yfi = (int)yf;
        int xci = xfi + 1, yci = yfi + 1;
        if (!((xfi >= 0) & (xci <= W) & (yfi >= 0) & (yci <= H))) continue;
        float wx1 = xd - xf, wx0 = (xf + 1.0f) - xd;
        float wy1 = yd - yf, wy0 = (yf + 1.0f) - yd;
        int X0 = min(max(xfi, 0), W - 1), X1 = min(max(xci, 0), W - 1);
        int Y0 = min(max(yfi, 0), H - 1), Y1 = min(max(yci, 0), H - 1);
        int lx0 = X0 - x0t, lx1 = X1 - x0t, ly0 = Y0 - y0t, ly1 = Y1 - y0t;
        bool ox0 = (unsigned)lx0 < (unsigned)TILE_W;
        bool ox1 = (unsigned)lx1 < (unsigned)TILE_W;
        bool oy0 = (unsigned)ly0 < (unsigned)TILE_H;
        bool oy1 = (unsigned)ly1 < (unsigned)TILE_H;
        float k0 = wx0 * wy0, k1 = wx1 * wy0, k2 = wx0 * wy1, k3 = wx1 * wy1;
        bool m0 = (k0 >= 0.25f) & ox0 & oy0;
        bool m1 = (k1 >= 0.25f) & ox1 & oy0;
        bool m2 = (k2 >= 0.25f) & ox0 & oy1;
        bool m3 = (k3 >= 0.25f) & ox1 & oy1;
        if (!(m0 | m1 | m2 | m3)) continue;
        int di = (int)(100.0f * sqrtf(f.x * f.x + f.y * f.y));
        float df = (float)di;
        int l00 = ly0 * TILE_W + lx0, l01 = ly0 * TILE_W + lx1;
        int l10 = ly1 * TILE_W + lx0, l11 = ly1 * TILE_W + lx1;
        bool g0 = m0 && ((float)du16[l00] - df <= MOTION_TH);
        bool g1 = m1 && ((float)du16[l01] - df <= MOTION_TH);
        bool g2 = m2 && ((float)du16[l10] - df <= MOTION_TH);
        bool g3 = m3 && ((float)du16[l11] - df <= MOTION_TH);
        if (!(g0 | g1 | g2 | g3)) continue;
        float v0 = im0[(b * C + 0) * HW + pix];
        float v1 = im0[(b * C + 1) * HW + pix];
        float v2 = im0[(b * C + 2) * HW + pix];
        float kk[4] = { k0, k1, k2, k3 };
        int   ll[4] = { l00, l01, l10, l11 };
        bool  gg[4] = { g0, g1, g2, g3 };
        #pragma unroll
        for (int c = 0; c < 4; ++c) {
            if (!gg[c]) continue;
            float k = kk[c];
            long long wq = (long long)__float2int_rn(k * W_SCALE);
            long long rq = (long long)__float2int_rn(v0 * k * V_SCALE);
            long long gq = (long long)__float2int_rn(v1 * k * V_SCALE);
            long long bq = (long long)__float2int_rn(v2 * k * V_SCALE);
            unsigned long long S =
                (unsigned long long)(wq + (rq << 16) + (gq << 32) + (bq << 48));
            atomicAdd(&aloc[ll[c]], S);
        }
    }
    __syncthreads();

    // ---- Phase E: plain-store owned cells (covers every acc cell exactly
    //      once across the grid; this replaces the acc memset) ----
    for (int i = t; i < CELLS; i += 1024) {
        int ly = i / TILE_W, lx = i - ly * TILE_W;
        acc[base + (y0t + ly) * W + (x0t + lx)] = aloc[i];
    }
}

// ---------------------------------------------------------------------------
// K3: far sources only — z-tested global u64 splat (reads final dbuf)
// ---------------------------------------------------------------------------
__global__ void far_splat(const float* __restrict__ im0,
                          const float* __restrict__ flow,
                          const int* __restrict__ dbuf,
                          unsigned long long* __restrict__ acc) {
    int n = blockIdx.x * blockDim.x + threadIdx.x;
    if (n >= N) return;
    float2 f = reinterpret_cast<const float2*>(flow)[n];
    if (is_near(f.x, f.y)) return;               // exact complement of tile path
    int b   = n / HW;
    int pix = n - b * HW;
    int y   = pix / W;
    int x   = pix - y * W;
    Splat s = make_splat(x, y, f.x, f.y);
    if (!s.valid) return;
    float v0 = im0[(b * C + 0) * HW + pix];
    float v1 = im0[(b * C + 1) * HW + pix];
    float v2 = im0[(b * C + 2) * HW + pix];
    int base = b * HW;
    #pragma unroll
    for (int c = 0; c < 4; ++c) {
        if (s.k[c] < 0.25f) continue;
        int idx = base + s.cy[c] * W + s.cx[c];
        float dg = (float)dbuf[idx];
        if (dg - s.df <= MOTION_TH) {
            float k = s.k[c];
            long long wq = (long long)__float2int_rn(k * W_SCALE);
            long long rq = (long long)__float2int_rn(v0 * k * V_SCALE);
            long long gq = (long long)__float2int_rn(v1 * k * V_SCALE);
            long long bq = (long long)__float2int_rn(v2 * k * V_SCALE);
            long long S  = wq + (rq << 16) + (gq << 32) + (bq << 48);
            atomicAdd(&acc[idx], (unsigned long long)S);
        }
    }
}

// ---------------------------------------------------------------------------
// K4: decode fields, out[c] = v[c] / max(w / C, eps)  (verified)
// ---------------------------------------------------------------------------
__global__ void norm_pass(const unsigned long long* __restrict__ acc,
                          float* __restrict__ out) {
    int n = blockIdx.x * blockDim.x + threadIdx.x;
    if (n >= N) return;
    int b   = n / HW;
    int pix = n - b * HW;

    long long T = (long long)acc[n];
    int wq = (int)(T & 0xffff);
    long long T1 = (T - wq) >> 16;
    int rq = (int)(((T1 & 0xffff) ^ 0x8000) - 0x8000);
    long long T2 = (T1 - rq) >> 16;
    int gq = (int)(((T2 & 0xffff) ^ 0x8000) - 0x8000);
    long long T3 = (T2 - gq) >> 16;
    int bq = (int)T3;

    float w  = (float)wq * (1.0f / W_SCALE);
    float r  = (float)rq * (1.0f / V_SCALE);
    float g  = (float)gq * (1.0f / V_SCALE);
    float bl = (float)bq * (1.0f / V_SCALE);

    float den = fmaxf(w * (1.0f / 3.0f), EPS);
    float inv = 1.0f / den;
    float* p = out + (size_t)b * C * HW + pix;
    p[0]      = r  * inv;
    p[HW]     = g  * inv;
    p[2 * HW] = bl * inv;
}

extern "C" void kernel_launch(void* const* d_in, const int* in_sizes, int n_in,
                              void* d_out, int out_size, void* d_ws, size_t ws_size,
                              hipStream_t stream) {
    const float* im0  = (const float*)d_in[0];
    const float* flow = (const float*)d_in[1];
    float* out = (float*)d_out;

    unsigned long long* acc = (unsigned long long*)d_ws;      // N x 8B
    int* dbuf = (int*)((char*)d_ws + (size_t)N * 8);          // N x 4B

    // Only dbuf needs zeroing: acc is fully written by tile_fused phase E
    // before far_splat's first atomicAdd.
    (void)hipMemsetAsync(dbuf, 0, (size_t)N * 4, stream);

    const int block = 256;
    const int grid  = (N + block - 1) / block;

    // Ordering: far depth -> fused tiles (merge far depth, write final dbuf,
    // near splat, plain-store acc) -> far splat (atomics into acc) -> norm.
    far_depth <<<grid,   block, 0, stream>>>(flow, dbuf);
    tile_fused<<<NTILES, 1024,  0, stream>>>(im0, flow, dbuf, acc);
    far_splat <<<grid,   block, 0, stream>>>(im0, flow, dbuf, acc);
    norm_pass <<<grid,   block, 0, stream>>>(acc, out);
}

// Round 4
// 374.102 us; speedup vs baseline: 2.5563x; 1.0626x over previous
//
#include <hip/hip_runtime.h>

// Problem constants (fixed by setup_inputs)
constexpr int B = 4, C = 3, H = 1080, W = 1920;
constexpr int HW = H * W;
constexpr int N = B * HW;                 // 8,294,400 source pixels
constexpr float MOTION_TH = 25.0f;        // 0.25 * 100
constexpr float EPS = 1e-5f;

// Packed fixed-point accumulator (verified):
//   field0 [ 0:16) w unsigned, scale 1024 ; field1..3 signed, scale 256
constexpr float W_SCALE = 1024.0f;
constexpr float V_SCALE = 256.0f;

// Destination-ownership tiling, fused depth+splat with worklist compaction.
//   NEAR source: |fx|<=63 && |fy|<=63  -> LDS path in the owning tile.
//   FAR  source: else (~0.33% of N(0,20) flow) -> global-atomic path.
// Tile 128x45 (exact 15x24 grid); scan region 256x173 (margin 64).
// LDS: acc u64 45K + depth u16 11.25K + worklist u16 16K = 74KB -> 2 WG/CU.
constexpr int   TILE_W = 128, TILE_H = 45;
constexpr int   MARG   = 64;
constexpr float NEAR_TH = 63.0f;
constexpr int   REG_W  = TILE_W + 2 * MARG;        // 256 (pow2 col mapping)
constexpr int   CELLS  = TILE_W * TILE_H;          // 5760
constexpr int   TX = W / TILE_W;                   // 15 (exact)
constexpr int   TY = H / TILE_H;                   // 24 (exact)
constexpr int   NTILES = B * TX * TY;              // 1440 (divisible by 8)
constexpr int   WL_CAP = 8192;                     // expected ~6110 +- 78

struct Splat {
    bool  valid;
    int   di;
    float df;
    float k[4];
    int   cx[4], cy[4];
};

// Identical arithmetic to the verified baseline (used by far kernels).
__device__ __forceinline__ Splat make_splat(int x, int y, float fx, float fy) {
    Splat s;
    float xd = (float)x + fx;
    float yd = (float)y + fy;
    float xf = floorf(xd), yf = floorf(yd);
    int xfi = (int)xf, yfi = (int)yf;
    int xci = xfi + 1, yci = yfi + 1;
    s.valid = (xfi >= 0) & (xci <= W) & (yfi >= 0) & (yci <= H);
    s.di = (int)(100.0f * sqrtf(fx * fx + fy * fy));
    s.df = (float)s.di;
    float wx1 = xd - xf, wx0 = (xf + 1.0f) - xd;
    float wy1 = yd - yf, wy0 = (yf + 1.0f) - yd;
    int x0 = min(max(xfi, 0), W - 1), x1 = min(max(xci, 0), W - 1);
    int y0 = min(max(yfi, 0), H - 1), y1 = min(max(yci, 0), H - 1);
    s.k[0] = wx0 * wy0; s.cx[0] = x0; s.cy[0] = y0;
    s.k[1] = wx1 * wy0; s.cx[1] = x1; s.cy[1] = y0;
    s.k[2] = wx0 * wy1; s.cx[2] = x0; s.cy[2] = y1;
    s.k[3] = wx1 * wy1; s.cx[3] = x1; s.cy[3] = y1;
    return s;
}

__device__ __forceinline__ bool is_near(float fx, float fy) {
    return (fabsf(fx) <= NEAR_TH) && (fabsf(fy) <= NEAR_TH);
}

// ---------------------------------------------------------------------------
// K1: far sources only — global scatter-max depth (grid-stride float4 scan)
// ---------------------------------------------------------------------------
__global__ void far_depth(const float* __restrict__ flow, int* __restrict__ dbuf) {
    const float4* flow4 = reinterpret_cast<const float4*>(flow);
    int stride = gridDim.x * blockDim.x;
    for (int i = blockIdx.x * blockDim.x + threadIdx.x; i < N / 2; i += stride) {
        float4 q = flow4[i];
        #pragma unroll
        for (int h = 0; h < 2; ++h) {
            float fx = h ? q.z : q.x;
            float fy = h ? q.w : q.y;
            if (is_near(fx, fy)) continue;
            int n   = 2 * i + h;
            int b   = n / HW;
            int pix = n - b * HW;
            int y   = pix / W;
            int x   = pix - y * W;
            Splat s = make_splat(x, y, fx, fy);
            if (!s.valid) continue;
            int base = b * HW;
            #pragma unroll
            for (int c = 0; c < 4; ++c)
                if (s.k[c] >= 0.25f)
                    atomicMax(&dbuf[base + s.cy[c] * W + s.cx[c]], s.di);
        }
    }
}

// ---------------------------------------------------------------------------
// K2: fused tile kernel with worklist compaction.
//   A0: bbox+near scan of region -> wave-compacted LDS worklist
//   A1: replay worklist: geometry + LDS scatter-max depth (i32 in acc region)
//   B : merge far depth from dbuf -> write final dbuf + du16
//   C : zero LDS acc
//   D : replay worklist: geometry + z-test vs du16 + LDS u64 accumulate
//   E : plain-store owned acc cells (exclusive ownership; replaces acc memset)
// ---------------------------------------------------------------------------
__global__ __launch_bounds__(1024, 8) void tile_fused(
        const float* __restrict__ im0,
        const float* __restrict__ flow,
        int* __restrict__ dbuf,
        unsigned long long* __restrict__ acc) {
    __shared__ unsigned long long aloc[CELLS];     // 46080 B
    __shared__ unsigned short     du16[CELLS];     // 11520 B
    __shared__ unsigned short     wl[WL_CAP];      // 16384 B  (total ~74 KB)
    __shared__ int                wl_cnt;
    int* dstage = (int*)aloc;                      // CELLS i32, low half of aloc

    const int t = threadIdx.x;
    // XCD-chunk swizzle: 1440 tiles / 8 XCDs = 180 contiguous tiles per XCD.
    int tile = (blockIdx.x & 7) * (NTILES / 8) + (blockIdx.x >> 3);
    int txi  = tile % TX;
    int tmp  = tile / TX;
    int tyi  = tmp % TY;
    int b    = tmp / TY;
    const int x0t = txi * TILE_W, y0t = tyi * TILE_H;
    const int base = b * HW;
    const float2* flow2 = reinterpret_cast<const float2*>(flow);

    if (t == 0) wl_cnt = 0;
    for (int i = t; i < CELLS; i += 1024) dstage[i] = 0;
    __syncthreads();

    // Thread -> (column, row-phase) mapping over the 256-wide region.
    const int   rxc   = t & (REG_W - 1);
    const int   gx    = x0t - MARG + rxc;
    const bool  colok = (gx >= 0) & (gx < W);
    const int   gy_hi = min(H, y0t + TILE_H + MARG);
    int gys = y0t - MARG + (t >> 8);
    if (gys < 0) gys += (-gys + 3) & ~3;           // stay on phase mod 4, >= 0
    const float gxf  = (float)gx;
    const float bxlo = (float)(x0t - 1),    bxhi = (float)(x0t + TILE_W);
    const float bylo = (float)(y0t - 1),    byhi = (float)(y0t + TILE_H);
    const int   lane = t & 63;

    // ---- Phase A0: bbox scan + wave-compacted worklist append ----
    if (colok) {
        const float2* fp = flow2 + base + (long)gys * W + gx;
        float2 fnext = (gys < gy_hi) ? *fp : float2{0.0f, 0.0f};
        for (int gy = gys; gy < gy_hi; gy += 4, fp += 4 * W) {
            float2 f = fnext;
            if (gy + 4 < gy_hi) fnext = fp[4 * W];
            float xd = gxf + f.x;
            float yd = (float)gy + f.y;
            bool hit = (xd >= bxlo) & (xd < bxhi) & (yd >= bylo) & (yd < byhi)
                     & (fabsf(f.x) <= NEAR_TH) & (fabsf(f.y) <= NEAR_TH);
            unsigned long long m = __ballot(hit);
            if (hit) {
                int rank = __popcll(m & ((1ull << lane) - 1ull));
                int bslot = 0;
                if (rank == 0) bslot = atomicAdd(&wl_cnt, __popcll(m));
                bslot = __shfl(bslot, __ffsll((long long)m) - 1);
                int slot = bslot + rank;
                if (slot < WL_CAP)
                    wl[slot] = (unsigned short)(((gy - (y0t - MARG)) << 8) | rxc);
            }
        }
    }
    __syncthreads();
    const int cnt = min(wl_cnt, WL_CAP);

    // ---- Phase A1: replay worklist -> LDS depth max ----
    for (int w = t; w < cnt; w += 1024) {
        int e  = wl[w];
        int rx = e & 255, ry = e >> 8;
        int gx2 = x0t - MARG + rx, gy2 = y0t - MARG + ry;
        float2 f = flow2[base + gy2 * W + gx2];
        float xd = (float)gx2 + f.x, yd = (float)gy2 + f.y;
        float xf = floorf(xd), yf = floorf(yd);
        int xfi = (int)xf, yfi = (int)yf;
        int xci = xfi + 1, yci = yfi + 1;
        if (!((xfi >= 0) & (xci <= W) & (yfi >= 0) & (yci <= H))) continue;
        float wx1 = xd - xf, wx0 = (xf + 1.0f) - xd;
        float wy1 = yd - yf, wy0 = (yf + 1.0f) - yd;
        int X0 = min(max(xfi, 0), W - 1), X1 = min(max(xci, 0), W - 1);
        int Y0 = min(max(yfi, 0), H - 1), Y1 = min(max(yci, 0), H - 1);
        int lx0 = X0 - x0t, lx1 = X1 - x0t, ly0 = Y0 - y0t, ly1 = Y1 - y0t;
        bool ox0 = (unsigned)lx0 < (unsigned)TILE_W;
        bool ox1 = (unsigned)lx1 < (unsigned)TILE_W;
        bool oy0 = (unsigned)ly0 < (unsigned)TILE_H;
        bool oy1 = (unsigned)ly1 < (unsigned)TILE_H;
        float k0 = wx0 * wy0, k1 = wx1 * wy0, k2 = wx0 * wy1, k3 = wx1 * wy1;
        bool m0 = (k0 >= 0.25f) & ox0 & oy0;
        bool m1 = (k1 >= 0.25f) & ox1 & oy0;
        bool m2 = (k2 >= 0.25f) & ox0 & oy1;
        bool m3 = (k3 >= 0.25f) & ox1 & oy1;
        if (!(m0 | m1 | m2 | m3)) continue;
        int di = (int)(100.0f * sqrtf(f.x * f.x + f.y * f.y));
        if (m0) atomicMax(&dstage[ly0 * TILE_W + lx0], di);
        if (m1) atomicMax(&dstage[ly0 * TILE_W + lx1], di);
        if (m2) atomicMax(&dstage[ly1 * TILE_W + lx0], di);
        if (m3) atomicMax(&dstage[ly1 * TILE_W + lx1], di);
    }
    __syncthreads();

    // ---- Phase B: merge far depth, write final dbuf + du16 ----
    for (int i = t; i < CELLS; i += 1024) {
        int ly = i / TILE_W, lx = i - ly * TILE_W;
        int g  = base + (y0t + ly) * W + (x0t + lx);
        int dm = max(dstage[i], dbuf[g]);          // far_depth already complete
        dbuf[g] = dm;                              // final depth for far_splat
        du16[i] = (unsigned short)min(dm, 65535);  // clamp preserves z-test
    }
    __syncthreads();                               // dstage reads done

    // ---- Phase C: zero acc (clobbers dstage) ----
    for (int i = t; i < CELLS; i += 1024) aloc[i] = 0ull;
    __syncthreads();

    // ---- Phase D: replay worklist -> z-test + LDS u64 accumulate ----
    for (int w = t; w < cnt; w += 1024) {
        int e  = wl[w];
        int rx = e & 255, ry = e >> 8;
        int gx2 = x0t - MARG + rx, gy2 = y0t - MARG + ry;
        int pix = gy2 * W + gx2;
        float2 f = flow2[base + pix];
        float xd = (float)gx2 + f.x, yd = (float)gy2 + f.y;
        float xf = floorf(xd), yf = floorf(yd);
        int xfi = (int)xf, yfi = (int)yf;
        int xci = xfi + 1, yci = yfi + 1;
        if (!((xfi >= 0) & (xci <= W) & (yfi >= 0) & (yci <= H))) continue;
        float wx1 = xd - xf, wx0 = (xf + 1.0f) - xd;
        float wy1 = yd - yf, wy0 = (yf + 1.0f) - yd;
        int X0 = min(max(xfi, 0), W - 1), X1 = min(max(xci, 0), W - 1);
        int Y0 = min(max(yfi, 0), H - 1), Y1 = min(max(yci, 0), H - 1);
        int lx0 = X0 - x0t, lx1 = X1 - x0t, ly0 = Y0 - y0t, ly1 = Y1 - y0t;
        bool ox0 = (unsigned)lx0 < (unsigned)TILE_W;
        bool ox1 = (unsigned)lx1 < (unsigned)TILE_W;
        bool oy0 = (unsigned)ly0 < (unsigned)TILE_H;
        bool oy1 = (unsigned)ly1 < (unsigned)TILE_H;
        float k0 = wx0 * wy0, k1 = wx1 * wy0, k2 = wx0 * wy1, k3 = wx1 * wy1;
        bool m0 = (k0 >= 0.25f) & ox0 & oy0;
        bool m1 = (k1 >= 0.25f) & ox1 & oy0;
        bool m2 = (k2 >= 0.25f) & ox0 & oy1;
        bool m3 = (k3 >= 0.25f) & ox1 & oy1;
        if (!(m0 | m1 | m2 | m3)) continue;
        int di = (int)(100.0f * sqrtf(f.x * f.x + f.y * f.y));
        float df = (float)di;
        int l00 = ly0 * TILE_W + lx0, l01 = ly0 * TILE_W + lx1;
        int l10 = ly1 * TILE_W + lx0, l11 = ly1 * TILE_W + lx1;
        bool g0 = m0 && ((float)du16[l00] - df <= MOTION_TH);
        bool g1 = m1 && ((float)du16[l01] - df <= MOTION_TH);
        bool g2 = m2 && ((float)du16[l10] - df <= MOTION_TH);
        bool g3 = m3 && ((float)du16[l11] - df <= MOTION_TH);
        if (!(g0 | g1 | g2 | g3)) continue;
        float v0 = im0[(b * C + 0) * HW + pix];
        float v1 = im0[(b * C + 1) * HW + pix];
        float v2 = im0[(b * C + 2) * HW + pix];
        float kk[4] = { k0, k1, k2, k3 };
        int   ll[4] = { l00, l01, l10, l11 };
        bool  gg[4] = { g0, g1, g2, g3 };
        #pragma unroll
        for (int c = 0; c < 4; ++c) {
            if (!gg[c]) continue;
            float k = kk[c];
            long long wq = (long long)__float2int_rn(k * W_SCALE);
            long long rq = (long long)__float2int_rn(v0 * k * V_SCALE);
            long long gq = (long long)__float2int_rn(v1 * k * V_SCALE);
            long long bq = (long long)__float2int_rn(v2 * k * V_SCALE);
            unsigned long long S =
                (unsigned long long)(wq + (rq << 16) + (gq << 32) + (bq << 48));
            atomicAdd(&aloc[ll[c]], S);
        }
    }
    __syncthreads();

    // ---- Phase E: plain-store owned cells (covers every acc cell exactly
    //      once across the grid; replaces the acc memset) ----
    for (int i = t; i < CELLS; i += 1024) {
        int ly = i / TILE_W, lx = i - ly * TILE_W;
        acc[base + (y0t + ly) * W + (x0t + lx)] = aloc[i];
    }
}

// ---------------------------------------------------------------------------
// K3: far sources only — z-tested global u64 splat (grid-stride float4 scan)
// ---------------------------------------------------------------------------
__global__ void far_splat(const float* __restrict__ im0,
                          const float* __restrict__ flow,
                          const int* __restrict__ dbuf,
                          unsigned long long* __restrict__ acc) {
    const float4* flow4 = reinterpret_cast<const float4*>(flow);
    int stride = gridDim.x * blockDim.x;
    for (int i = blockIdx.x * blockDim.x + threadIdx.x; i < N / 2; i += stride) {
        float4 q = flow4[i];
        #pragma unroll
        for (int h = 0; h < 2; ++h) {
            float fx = h ? q.z : q.x;
            float fy = h ? q.w : q.y;
            if (is_near(fx, fy)) continue;       // exact complement of tile path
            int n   = 2 * i + h;
            int b   = n / HW;
            int pix = n - b * HW;
            int y   = pix / W;
            int x   = pix - y * W;
            Splat s = make_splat(x, y, fx, fy);
            if (!s.valid) continue;
            float v0 = im0[(b * C + 0) * HW + pix];
            float v1 = im0[(b * C + 1) * HW + pix];
            float v2 = im0[(b * C + 2) * HW + pix];
            int base = b * HW;
            #pragma unroll
            for (int c = 0; c < 4; ++c) {
                if (s.k[c] < 0.25f) continue;
                int idx = base + s.cy[c] * W + s.cx[c];
                float dg = (float)dbuf[idx];
                if (dg - s.df <= MOTION_TH) {
                    float k = s.k[c];
                    long long wq = (long long)__float2int_rn(k * W_SCALE);
                    long long rq = (long long)__float2int_rn(v0 * k * V_SCALE);
                    long long gq = (long long)__float2int_rn(v1 * k * V_SCALE);
                    long long bq = (long long)__float2int_rn(v2 * k * V_SCALE);
                    long long S  = wq + (rq << 16) + (gq << 32) + (bq << 48);
                    atomicAdd(&acc[idx], (unsigned long long)S);
                }
            }
        }
    }
}

// ---------------------------------------------------------------------------
// K4: decode fields, out[c] = v[c] / max(w / C, eps)  (2 px/thread)
// ---------------------------------------------------------------------------
__global__ void norm_pass(const unsigned long long* __restrict__ acc,
                          float* __restrict__ out) {
    int i = blockIdx.x * blockDim.x + threadIdx.x;   // pixel-pair index
    if (i >= N / 2) return;
    ulonglong2 T2 = reinterpret_cast<const ulonglong2*>(acc)[i];
    int n   = 2 * i;
    int b   = n / HW;            // HW even: pair never straddles batches
    int pix = n - b * HW;

    float res[6];
    #pragma unroll
    for (int h = 0; h < 2; ++h) {
        long long T = (long long)(h ? T2.y : T2.x);
        int wq = (int)(T & 0xffff);
        long long T1 = (T - wq) >> 16;
        int rq = (int)(((T1 & 0xffff) ^ 0x8000) - 0x8000);
        long long Tt = (T1 - rq) >> 16;
        int gq = (int)(((Tt & 0xffff) ^ 0x8000) - 0x8000);
        long long T3 = (Tt - gq) >> 16;
        int bq = (int)T3;

        float w  = (float)wq * (1.0f / W_SCALE);
        float den = fmaxf(w * (1.0f / 3.0f), EPS);
        float inv = 1.0f / den;
        res[0 + h] = (float)rq * (1.0f / V_SCALE) * inv;
        res[2 + h] = (float)gq * (1.0f / V_SCALE) * inv;
        res[4 + h] = (float)bq * (1.0f / V_SCALE) * inv;
    }
    float* p = out + (size_t)b * C * HW + pix;
    *reinterpret_cast<float2*>(p)          = float2{res[0], res[1]};
    *reinterpret_cast<float2*>(p + HW)     = float2{res[2], res[3]};
    *reinterpret_cast<float2*>(p + 2 * HW) = float2{res[4], res[5]};
}

extern "C" void kernel_launch(void* const* d_in, const int* in_sizes, int n_in,
                              void* d_out, int out_size, void* d_ws, size_t ws_size,
                              hipStream_t stream) {
    const float* im0  = (const float*)d_in[0];
    const float* flow = (const float*)d_in[1];
    float* out = (float*)d_out;

    unsigned long long* acc = (unsigned long long*)d_ws;      // N x 8B
    int* dbuf = (int*)((char*)d_ws + (size_t)N * 8);          // N x 4B

    // Only dbuf needs zeroing: acc is fully written by tile_fused phase E
    // before far_splat's first atomicAdd.
    (void)hipMemsetAsync(dbuf, 0, (size_t)N * 4, stream);

    const int block = 256;
    const int sgrid = 2048;                       // grid-stride far scans

    // Ordering: far depth -> fused tiles (merge far depth, write final dbuf,
    // near splat, plain-store acc) -> far splat (atomics into acc) -> norm.
    far_depth <<<sgrid,  block, 0, stream>>>(flow, dbuf);
    tile_fused<<<NTILES, 1024,  0, stream>>>(im0, flow, dbuf, acc);
    far_splat <<<sgrid,  block, 0, stream>>>(im0, flow, dbuf, acc);
    norm_pass <<<(N / 2 + block - 1) / block, block, 0, stream>>>(acc, out);
}